// Round 6
// baseline (58.488 us; speedup 1.0000x reference)
//
#include <hip/hip_runtime.h>
#include <math.h>
#include <stdint.h>

#define RESO 128
#define NUM_FEAT 16
#define DATA_DIM 16
#define MLP_W 128
#define NFREQ 4
#define BATCH 1024
#define NS 442
#define NT 256
#define NWAVES 4
#define HALF_A 224
#define STEPF ((float)(1.3 / 128.0))

// ---------------- Morton ----------------
static __device__ __forceinline__ uint32_t expand_bits(uint32_t v) {
    v = (v * 65537u) & 4278190335u;
    v = (v * 257u)   & 251719695u;
    v = (v * 17u)    & 3272356035u;
    v = (v * 5u)     & 1227133513u;
    return v;
}
static __device__ __forceinline__ uint32_t morton3d(uint32_t x, uint32_t y, uint32_t z) {
    return expand_bits(x) | (expand_bits(y) << 1) | (expand_bits(z) << 2);
}

// -------- Main: one block (256 thr) per (ray, half); partials to d_ws --------
__global__ __launch_bounds__(NT) void nerf_main_kernel(
    const float* __restrict__ rays_o, const float* __restrict__ rays_d,
    const float* __restrict__ grid, const float* __restrict__ cbg,
    const float* __restrict__ W1g, const float* __restrict__ b1g,
    const float* __restrict__ W2g, const float* __restrict__ b2g,
    float* __restrict__ part, float* __restrict__ out_alpha) {

    __shared__ __align__(16) float cbs[NUM_FEAT * DATA_DIM];
    __shared__ __align__(16) float pe_b1s[MLP_W];   // b1[o] + pe . W1[16:40, o]
    __shared__ float wtot[NWAVES];
    __shared__ float wred[NWAVES][4];

    const int blk = blockIdx.x;
    const int b = blk >> 1;
    const int h = blk & 1;
    const int t = threadIdx.x;
    const int wid = t >> 6;
    const int lane = t & 63;

    // per-ray setup (broadcast loads)
    const float o0 = rays_o[b * 3 + 0], o1 = rays_o[b * 3 + 1], o2 = rays_o[b * 3 + 2];
    const float d0 = rays_d[b * 3 + 0], d1 = rays_d[b * 3 + 1], d2 = rays_d[b * 3 + 2];
    const float R = 1.3f;
    float sd0 = (fabsf(d0) < 1e-8f) ? 1e-8f : d0;
    float sd1 = (fabsf(d1) < 1e-8f) ? 1e-8f : d1;
    float sd2 = (fabsf(d2) < 1e-8f) ? 1e-8f : d2;
    float ta0 = (-R - o0) / sd0, tb0 = (R - o0) / sd0;
    float ta1 = (-R - o1) / sd1, tb1 = (R - o1) / sd1;
    float ta2 = (-R - o2) / sd2, tb2 = (R - o2) / sd2;
    float tmin = fmaxf(fmaxf(fminf(ta0, tb0), fminf(ta1, tb1)), fminf(ta2, tb2));
    float tmax = fminf(fminf(fmaxf(ta0, tb0), fmaxf(ta1, tb1)), fmaxf(ta2, tb2));
    float tnear = fmaxf(tmin, 0.0f);
    float nrm = sqrtf(d0 * d0 + d1 * d1 + d2 * d2);

    const int s0 = h ? HALF_A : 0;
    const int scount = h ? (NS - HALF_A) : HALF_A;
    const int s = s0 + t;

    // ---- uniform early-out for half B when its first sample is inactive ----
    if (h) {
        float tm0 = tnear + ((float)s0 + 0.5f) * STEPF;
        float qx = o0 + d0 * tm0, qy = o1 + d1 * tm0, qz = o2 + d2 * tm0;
        bool act0 = (tm0 < tmax) && (fabsf(qx) <= R) && (fabsf(qy) <= R) && (fabsf(qz) <= R);
        if (!act0) {   // prefix property: no active samples in this half
            if (t < scount) out_alpha[b * NS + s] = 0.0f;
            if (t == 0) {
                float* P = part + blk * 8;
                P[0] = 0.0f; P[1] = 0.0f; P[2] = 0.0f; P[3] = 0.0f; P[4] = 1.0f;
            }
            return;
        }
    }

    // stage codebook
    cbs[t] = cbg[t];

    // fold positional encoding + b1 into per-ray bias (once per block)
    if (t < MLP_W) {
        float acc = b1g[t];
#pragma unroll
        for (int f = 0; f < NFREQ; ++f) {
            float fr = (float)(1 << f);
            acc = fmaf(__sinf(d0 * fr), W1g[(DATA_DIM + f * 6 + 0) * MLP_W + t], acc);
            acc = fmaf(__sinf(d1 * fr), W1g[(DATA_DIM + f * 6 + 1) * MLP_W + t], acc);
            acc = fmaf(__sinf(d2 * fr), W1g[(DATA_DIM + f * 6 + 2) * MLP_W + t], acc);
            acc = fmaf(__cosf(d0 * fr), W1g[(DATA_DIM + f * 6 + 3) * MLP_W + t], acc);
            acc = fmaf(__cosf(d1 * fr), W1g[(DATA_DIM + f * 6 + 4) * MLP_W + t], acc);
            acc = fmaf(__cosf(d2 * fr), W1g[(DATA_DIM + f * 6 + 5) * MLP_W + t], acc);
        }
        pe_b1s[t] = acc;
    }
    __syncthreads();

    const bool lane_active = (t < scount);

    float i0 = tnear + (float)s * STEPF;
    float i1 = tnear + (float)(s + 1) * STEPF;
    float tm = 0.5f * (i0 + i1);
    float delta = (i1 - i0) * nrm;
    float px = o0 + d0 * tm, py = o1 + d1 * tm, pz = o2 + d2 * tm;
    bool m = lane_active && (tm < tmax) &&
             (fabsf(px) <= R) && (fabsf(py) <= R) && (fabsf(pz) <= R);

    float alpha = 0.0f, c0 = 0.0f, c1 = 0.0f, c2 = 0.0f;

    float x[DATA_DIM];
#pragma unroll
    for (int j = 0; j < DATA_DIM; ++j) x[j] = 0.0f;

    if (m) {
        float gx = (px / R + 1.0f) * (RESO * 0.5f);
        float gy = (py / R + 1.0f) * (RESO * 0.5f);
        float gz = (pz / R + 1.0f) * (RESO * 0.5f);
        float flx = floorf(gx), fly = floorf(gy), flz = floorf(gz);
        float ox = gx - flx, oy = gy - fly, oz = gz - flz;
        int ix = (int)flx, iy = (int)fly, iz = (int)flz;

#pragma unroll
        for (int n = 0; n < 8; ++n) {
            int bx = (n >> 2) & 1, by = (n >> 1) & 1, bz = n & 1;
            int cx = min(max(ix + bx, 0), RESO - 1);
            int cy = min(max(iy + by, 0), RESO - 1);
            int cz = min(max(iz + bz, 0), RESO - 1);
            uint32_t mi = morton3d((uint32_t)cx, (uint32_t)cy, (uint32_t)cz);
            float wv = (bx ? ox : 1.0f - ox) * (by ? oy : 1.0f - oy) * (bz ? oz : 1.0f - oz);

            // on-demand VQ: argmax of grid[mi, 0..15] (first-max-wins)
            const float4* g4 = (const float4*)(grid + ((size_t)mi << 4));
            float4 A = g4[0], B = g4[1], C = g4[2], D = g4[3];
            float v[16] = {A.x, A.y, A.z, A.w, B.x, B.y, B.z, B.w,
                           C.x, C.y, C.z, C.w, D.x, D.y, D.z, D.w};
            float bestv = v[0];
            int bi = 0;
#pragma unroll
            for (int j = 1; j < 16; ++j) {
                bi = (v[j] > bestv) ? j : bi;
                bestv = fmaxf(v[j], bestv);
            }

            const float4* cbr = (const float4*)&cbs[bi * DATA_DIM];
            float4 ca = cbr[0], cb4 = cbr[1], cc = cbr[2], cd = cbr[3];
            x[0]  = fmaf(wv, ca.x,  x[0]);  x[1]  = fmaf(wv, ca.y,  x[1]);
            x[2]  = fmaf(wv, ca.z,  x[2]);  x[3]  = fmaf(wv, ca.w,  x[3]);
            x[4]  = fmaf(wv, cb4.x, x[4]);  x[5]  = fmaf(wv, cb4.y, x[5]);
            x[6]  = fmaf(wv, cb4.z, x[6]);  x[7]  = fmaf(wv, cb4.w, x[7]);
            x[8]  = fmaf(wv, cc.x,  x[8]);  x[9]  = fmaf(wv, cc.y,  x[9]);
            x[10] = fmaf(wv, cc.z,  x[10]); x[11] = fmaf(wv, cc.w,  x[11]);
            x[12] = fmaf(wv, cd.x,  x[12]); x[13] = fmaf(wv, cd.y,  x[13]);
            x[14] = fmaf(wv, cd.z,  x[14]); x[15] = fmaf(wv, cd.w,  x[15]);
        }
    }

    // MLP under a wave-uniform guard; W1 read in NATIVE layout via s_load_dwordx4:
    // W1[j*128 + 4q + k] feeds accumulator k of output-quad q directly.
    if (__any((int)m)) {
        float p0 = b2g[0], p1 = b2g[1], p2 = b2g[2], p3 = b2g[3];
        for (int q = 0; q < MLP_W / 4; ++q) {
            const float4 pb = *(const float4*)&pe_b1s[q * 4];   // ds_read_b128
            float a0 = pb.x, a1 = pb.y, a2 = pb.z, a3 = pb.w;
#pragma unroll
            for (int j = 0; j < DATA_DIM; ++j) {
                float4 w = *(const float4*)&W1g[j * MLP_W + q * 4];  // uniform -> s_load
                a0 = fmaf(x[j], w.x, a0);
                a1 = fmaf(x[j], w.y, a1);
                a2 = fmaf(x[j], w.z, a2);
                a3 = fmaf(x[j], w.w, a3);
            }
            float h0 = fmaxf(a0, 0.0f), h1 = fmaxf(a1, 0.0f);
            float h2 = fmaxf(a2, 0.0f), h3 = fmaxf(a3, 0.0f);
            float4 w20 = *(const float4*)&W2g[(q * 4 + 0) * 4];      // uniform -> s_load
            float4 w21 = *(const float4*)&W2g[(q * 4 + 1) * 4];
            float4 w22 = *(const float4*)&W2g[(q * 4 + 2) * 4];
            float4 w23 = *(const float4*)&W2g[(q * 4 + 3) * 4];
            p0 = fmaf(h0, w20.x, p0); p1 = fmaf(h0, w20.y, p1);
            p2 = fmaf(h0, w20.z, p2); p3 = fmaf(h0, w20.w, p3);
            p0 = fmaf(h1, w21.x, p0); p1 = fmaf(h1, w21.y, p1);
            p2 = fmaf(h1, w21.z, p2); p3 = fmaf(h1, w21.w, p3);
            p0 = fmaf(h2, w22.x, p0); p1 = fmaf(h2, w22.y, p1);
            p2 = fmaf(h2, w22.z, p2); p3 = fmaf(h2, w22.w, p3);
            p0 = fmaf(h3, w23.x, p0); p1 = fmaf(h3, w23.y, p1);
            p2 = fmaf(h3, w23.z, p2); p3 = fmaf(h3, w23.w, p3);
        }
        if (m) {
            float dens = fmaxf(p0, 0.0f);
            alpha = 1.0f - __expf(-dens * delta);
            c0 = 1.0f / (1.0f + __expf(-p1));
            c1 = 1.0f / (1.0f + __expf(-p2));
            c2 = 1.0f / (1.0f + __expf(-p3));
        }
    }

    // ---- local compositing: wave64 shuffle product-scan + cross-wave combine ----
    float inc = 1.0f - alpha + 1e-10f;
#pragma unroll
    for (int off = 1; off < 64; off <<= 1) {
        float u = __shfl_up(inc, off, 64);
        if (lane >= off) inc *= u;
    }
    float excl = __shfl_up(inc, 1, 64);
    if (lane == 0) excl = 1.0f;
    if (lane == 63) wtot[wid] = inc;
    __syncthreads();

    float wpre = 1.0f;
#pragma unroll
    for (int w = 0; w < NWAVES; ++w)
        if (w < wid) wpre *= wtot[w];
    float T = wpre * excl;                 // T relative to this half's start
    float wgt = alpha * T;
    float r0 = wgt * c0, r1 = wgt * c1, r2 = wgt * c2, rw = wgt;

    if (lane_active) out_alpha[b * NS + s] = alpha;

    // ---- partial reduction ----
#pragma unroll
    for (int off = 32; off >= 1; off >>= 1) {
        r0 += __shfl_down(r0, off, 64);
        r1 += __shfl_down(r1, off, 64);
        r2 += __shfl_down(r2, off, 64);
        rw += __shfl_down(rw, off, 64);
    }
    if (lane == 0) { wred[wid][0] = r0; wred[wid][1] = r1; wred[wid][2] = r2; wred[wid][3] = rw; }
    __syncthreads();
    if (t == 0) {
        float s0r = 0, s1r = 0, s2r = 0, swr = 0;
#pragma unroll
        for (int i = 0; i < NWAVES; ++i) {
            s0r += wred[i][0]; s1r += wred[i][1]; s2r += wred[i][2]; swr += wred[i][3];
        }
        float P = wtot[0] * wtot[1] * wtot[2] * wtot[3];  // this half's transmittance
        float* Pp = part + blk * 8;
        Pp[0] = s0r; Pp[1] = s1r; Pp[2] = s2r; Pp[3] = swr; Pp[4] = P;
    }
}

// -------- Combine: rgb = partA + P_A * partB, plus white background --------
__global__ __launch_bounds__(256) void combine_kernel(const float* __restrict__ part,
                                                      float* __restrict__ out_rgb) {
    int b = blockIdx.x * blockDim.x + threadIdx.x;
    if (b >= BATCH) return;
    const float* A = part + (2 * b + 0) * 8;
    const float* B = part + (2 * b + 1) * 8;
    float PA = A[4];
    float r0 = A[0] + PA * B[0];
    float r1 = A[1] + PA * B[1];
    float r2 = A[2] + PA * B[2];
    float rw = A[3] + PA * B[3];
    float bg = 1.0f - rw;
    out_rgb[b * 3 + 0] = r0 + bg;
    out_rgb[b * 3 + 1] = r1 + bg;
    out_rgb[b * 3 + 2] = r2 + bg;
}

extern "C" void kernel_launch(void* const* d_in, const int* in_sizes, int n_in,
                              void* d_out, int out_size, void* d_ws, size_t ws_size,
                              hipStream_t stream) {
    const float* rays_o   = (const float*)d_in[0];
    const float* rays_d   = (const float*)d_in[1];
    const float* grid     = (const float*)d_in[2];
    const float* codebook = (const float*)d_in[3];
    const float* W1       = (const float*)d_in[4];
    const float* b1       = (const float*)d_in[5];
    const float* W2       = (const float*)d_in[6];
    const float* b2       = (const float*)d_in[7];
    float* out = (float*)d_out;

    float* part = (float*)d_ws;   // 2048 * 8 floats = 64 KB

    nerf_main_kernel<<<BATCH * 2, NT, 0, stream>>>(
        rays_o, rays_d, grid, codebook, W1, b1, W2, b2,
        part, out + BATCH * 3 /* alpha: 1024*442 */);
    combine_kernel<<<BATCH / 256, 256, 0, stream>>>(part, out /* rgb: 1024*3 */);
}

// Round 7
// 49.329 us; speedup vs baseline: 1.1857x; 1.1857x over previous
//
#include <hip/hip_runtime.h>
#include <math.h>
#include <stdint.h>

#define RESO 128
#define NUM_FEAT 16
#define DATA_DIM 16
#define MLP_W 128
#define NFREQ 4
#define BATCH 1024
#define NS 442
#define NT 512
#define NWAVES 8
#define STEPF ((float)(1.3 / 128.0))

// ---------------- Morton ----------------
static __device__ __forceinline__ uint32_t expand_bits(uint32_t v) {
    v = (v * 65537u) & 4278190335u;
    v = (v * 257u)   & 251719695u;
    v = (v * 17u)    & 3272356035u;
    v = (v * 5u)     & 1227133513u;
    return v;
}
static __device__ __forceinline__ uint32_t morton3d(uint32_t x, uint32_t y, uint32_t z) {
    return expand_bits(x) | (expand_bits(y) << 1) | (expand_bits(z) << 2);
}

// ------- Pre-pass: W1 data-part transpose -> [128][16] (tiny) -------
__global__ __launch_bounds__(128) void w1_prep_kernel(const float* __restrict__ W1,
                                                      float* __restrict__ W1dT) {
    int o = threadIdx.x;  // 0..127
#pragma unroll
    for (int j = 0; j < DATA_DIM; ++j) W1dT[o * DATA_DIM + j] = W1[j * MLP_W + o];
}

// ---------------- Main: one block (512 thr, 8 waves) per ray ----------------
__global__ __launch_bounds__(NT) void nerf_main_kernel(
    const float* __restrict__ rays_o, const float* __restrict__ rays_d,
    const float* __restrict__ grid, const float* __restrict__ cbg,
    const float* __restrict__ W1g, const float* __restrict__ b1g,
    const float* __restrict__ W2g, const float* __restrict__ b2g,
    const float* __restrict__ W1dT,
    float* __restrict__ out_rgb, float* __restrict__ out_alpha) {

    __shared__ __align__(16) float cbs[NUM_FEAT * DATA_DIM];
    __shared__ float pe_b1s[MLP_W];     // b1[o] + pe . W1[16:40, o]
    __shared__ float wtot[NWAVES];      // per-wave transmittance products
    __shared__ float wred[NWAVES][4];

    const int b = blockIdx.x;
    const int t = threadIdx.x;
    const int wid = t >> 6;
    const int lane = t & 63;

    // per-ray setup (broadcast loads)
    const float o0 = rays_o[b * 3 + 0], o1 = rays_o[b * 3 + 1], o2 = rays_o[b * 3 + 2];
    const float d0 = rays_d[b * 3 + 0], d1 = rays_d[b * 3 + 1], d2 = rays_d[b * 3 + 2];
    const float R = 1.3f;
    float sd0 = (fabsf(d0) < 1e-8f) ? 1e-8f : d0;
    float sd1 = (fabsf(d1) < 1e-8f) ? 1e-8f : d1;
    float sd2 = (fabsf(d2) < 1e-8f) ? 1e-8f : d2;
    float ta0 = (-R - o0) / sd0, tb0 = (R - o0) / sd0;
    float ta1 = (-R - o1) / sd1, tb1 = (R - o1) / sd1;
    float ta2 = (-R - o2) / sd2, tb2 = (R - o2) / sd2;
    float tmin = fmaxf(fmaxf(fminf(ta0, tb0), fminf(ta1, tb1)), fminf(ta2, tb2));
    float tmax = fminf(fminf(fmaxf(ta0, tb0), fmaxf(ta1, tb1)), fmaxf(ta2, tb2));
    float tnear = fmaxf(tmin, 0.0f);
    float nrm = sqrtf(d0 * d0 + d1 * d1 + d2 * d2);

    // stage codebook (256 values)
    if (t < NUM_FEAT * DATA_DIM) cbs[t] = cbg[t];

    // fold positional encoding + b1 into per-ray bias (once per block)
    if (t < MLP_W) {
        float acc = b1g[t];
#pragma unroll
        for (int f = 0; f < NFREQ; ++f) {
            float fr = (float)(1 << f);
            acc = fmaf(__sinf(d0 * fr), W1g[(DATA_DIM + f * 6 + 0) * MLP_W + t], acc);
            acc = fmaf(__sinf(d1 * fr), W1g[(DATA_DIM + f * 6 + 1) * MLP_W + t], acc);
            acc = fmaf(__sinf(d2 * fr), W1g[(DATA_DIM + f * 6 + 2) * MLP_W + t], acc);
            acc = fmaf(__cosf(d0 * fr), W1g[(DATA_DIM + f * 6 + 3) * MLP_W + t], acc);
            acc = fmaf(__cosf(d1 * fr), W1g[(DATA_DIM + f * 6 + 4) * MLP_W + t], acc);
            acc = fmaf(__cosf(d2 * fr), W1g[(DATA_DIM + f * 6 + 5) * MLP_W + t], acc);
        }
        pe_b1s[t] = acc;
    }
    __syncthreads();

    const int s = t;
    const bool lane_active = (s < NS);

    float i0 = tnear + (float)s * STEPF;
    float i1 = tnear + (float)(s + 1) * STEPF;
    float tm = 0.5f * (i0 + i1);
    float delta = (i1 - i0) * nrm;
    float px = o0 + d0 * tm, py = o1 + d1 * tm, pz = o2 + d2 * tm;
    bool m = lane_active && (tm < tmax) &&
             (fabsf(px) <= R) && (fabsf(py) <= R) && (fabsf(pz) <= R);

    float alpha = 0.0f, c0 = 0.0f, c1 = 0.0f, c2 = 0.0f;

    float x[DATA_DIM];
#pragma unroll
    for (int j = 0; j < DATA_DIM; ++j) x[j] = 0.0f;

    if (m) {
        float gx = (px / R + 1.0f) * (RESO * 0.5f);
        float gy = (py / R + 1.0f) * (RESO * 0.5f);
        float gz = (pz / R + 1.0f) * (RESO * 0.5f);
        float flx = floorf(gx), fly = floorf(gy), flz = floorf(gz);
        float ox = gx - flx, oy = gy - fly, oz = gz - flz;
        int ix = (int)flx, iy = (int)fly, iz = (int)flz;

        // ---- phase 1: all 8 corner addresses + trilinear weights ----
        uint32_t mi[8];
        float wn[8];
        float bestv[8];
        int bi[8];
#pragma unroll
        for (int n = 0; n < 8; ++n) {
            int bx = (n >> 2) & 1, by = (n >> 1) & 1, bz = n & 1;
            int cx = min(max(ix + bx, 0), RESO - 1);
            int cy = min(max(iy + by, 0), RESO - 1);
            int cz = min(max(iz + bz, 0), RESO - 1);
            mi[n] = morton3d((uint32_t)cx, (uint32_t)cy, (uint32_t)cz);
            wn[n] = (bx ? ox : 1.0f - ox) * (by ? oy : 1.0f - oy) * (bz ? oz : 1.0f - oz);
            bestv[n] = -3.4e38f;
            bi[n] = 0;
        }

        // ---- phase 2: quarter-separable argmax; 8 independent loads in
        // flight per quarter, consume in issue order (vmcnt staggering) ----
        const float4* gq = (const float4*)grid;
#pragma unroll
        for (int q = 0; q < 4; ++q) {
            float4 t4[8];
#pragma unroll
            for (int n = 0; n < 8; ++n) t4[n] = gq[(size_t)mi[n] * 4 + q];
#pragma unroll
            for (int n = 0; n < 8; ++n) {
                float v0 = t4[n].x, v1 = t4[n].y, v2 = t4[n].z, v3 = t4[n].w;
                int j0 = q * 4;
                bi[n] = (v0 > bestv[n]) ? (j0 + 0) : bi[n]; bestv[n] = fmaxf(v0, bestv[n]);
                bi[n] = (v1 > bestv[n]) ? (j0 + 1) : bi[n]; bestv[n] = fmaxf(v1, bestv[n]);
                bi[n] = (v2 > bestv[n]) ? (j0 + 2) : bi[n]; bestv[n] = fmaxf(v2, bestv[n]);
                bi[n] = (v3 > bestv[n]) ? (j0 + 3) : bi[n]; bestv[n] = fmaxf(v3, bestv[n]);
            }
        }

        // ---- phase 3: codebook blend ----
#pragma unroll
        for (int n = 0; n < 8; ++n) {
            const float4* cbr = (const float4*)&cbs[bi[n] * DATA_DIM];
            float4 ca = cbr[0], cb4 = cbr[1], cc = cbr[2], cd = cbr[3];
            float wv = wn[n];
            x[0]  = fmaf(wv, ca.x,  x[0]);  x[1]  = fmaf(wv, ca.y,  x[1]);
            x[2]  = fmaf(wv, ca.z,  x[2]);  x[3]  = fmaf(wv, ca.w,  x[3]);
            x[4]  = fmaf(wv, cb4.x, x[4]);  x[5]  = fmaf(wv, cb4.y, x[5]);
            x[6]  = fmaf(wv, cb4.z, x[6]);  x[7]  = fmaf(wv, cb4.w, x[7]);
            x[8]  = fmaf(wv, cc.x,  x[8]);  x[9]  = fmaf(wv, cc.y,  x[9]);
            x[10] = fmaf(wv, cc.z,  x[10]); x[11] = fmaf(wv, cc.w,  x[11]);
            x[12] = fmaf(wv, cd.x,  x[12]); x[13] = fmaf(wv, cd.y,  x[13]);
            x[14] = fmaf(wv, cd.z,  x[14]); x[15] = fmaf(wv, cd.w,  x[15]);
        }
    }

    // MLP under a wave-uniform guard so weight loads stay scalar (s_load)
    if (__any((int)m)) {
        float p0 = b2g[0], p1 = b2g[1], p2 = b2g[2], p3 = b2g[3];
#pragma unroll 4
        for (int o = 0; o < MLP_W; ++o) {
            float acc = pe_b1s[o];                                   // LDS broadcast
            const float4* wr = (const float4*)(W1dT + o * DATA_DIM); // uniform -> s_load
            float4 wa = wr[0], wb = wr[1], wc = wr[2], wd = wr[3];
            acc = fmaf(x[0],  wa.x, acc);  acc = fmaf(x[1],  wa.y, acc);
            acc = fmaf(x[2],  wa.z, acc);  acc = fmaf(x[3],  wa.w, acc);
            acc = fmaf(x[4],  wb.x, acc);  acc = fmaf(x[5],  wb.y, acc);
            acc = fmaf(x[6],  wb.z, acc);  acc = fmaf(x[7],  wb.w, acc);
            acc = fmaf(x[8],  wc.x, acc);  acc = fmaf(x[9],  wc.y, acc);
            acc = fmaf(x[10], wc.z, acc);  acc = fmaf(x[11], wc.w, acc);
            acc = fmaf(x[12], wd.x, acc);  acc = fmaf(x[13], wd.y, acc);
            acc = fmaf(x[14], wd.z, acc);  acc = fmaf(x[15], wd.w, acc);
            float h = fmaxf(acc, 0.0f);
            float4 w2 = *(const float4*)(W2g + o * 4);               // uniform -> s_load
            p0 = fmaf(h, w2.x, p0);
            p1 = fmaf(h, w2.y, p1);
            p2 = fmaf(h, w2.z, p2);
            p3 = fmaf(h, w2.w, p3);
        }
        if (m) {
            float dens = fmaxf(p0, 0.0f);
            alpha = 1.0f - __expf(-dens * delta);
            c0 = 1.0f / (1.0f + __expf(-p1));
            c1 = 1.0f / (1.0f + __expf(-p2));
            c2 = 1.0f / (1.0f + __expf(-p3));
        }
    }

    // ---- compositing: wave64 shuffle product-scan + cross-wave combine ----
    float inc = 1.0f - alpha + 1e-10f;
#pragma unroll
    for (int off = 1; off < 64; off <<= 1) {
        float u = __shfl_up(inc, off, 64);
        if (lane >= off) inc *= u;
    }
    float excl = __shfl_up(inc, 1, 64);
    if (lane == 0) excl = 1.0f;
    if (lane == 63) wtot[wid] = inc;   // wave total product
    __syncthreads();

    float wpre = 1.0f;                 // product of preceding waves
#pragma unroll
    for (int w = 0; w < NWAVES; ++w)
        if (w < wid) wpre *= wtot[w];
    float T = wpre * excl;
    float wgt = alpha * T;
    float r0 = wgt * c0, r1 = wgt * c1, r2 = wgt * c2, rw = wgt;

    if (lane_active) out_alpha[b * NS + s] = alpha;

    // ---- final rgb reduction ----
#pragma unroll
    for (int off = 32; off >= 1; off >>= 1) {
        r0 += __shfl_down(r0, off, 64);
        r1 += __shfl_down(r1, off, 64);
        r2 += __shfl_down(r2, off, 64);
        rw += __shfl_down(rw, off, 64);
    }
    if (lane == 0) { wred[wid][0] = r0; wred[wid][1] = r1; wred[wid][2] = r2; wred[wid][3] = rw; }
    __syncthreads();
    if (t == 0) {
        float s0 = 0, s1 = 0, s2 = 0, sw = 0;
#pragma unroll
        for (int i = 0; i < NWAVES; ++i) {
            s0 += wred[i][0]; s1 += wred[i][1]; s2 += wred[i][2]; sw += wred[i][3];
        }
        float bg = 1.0f - sw;
        out_rgb[b * 3 + 0] = s0 + bg;
        out_rgb[b * 3 + 1] = s1 + bg;
        out_rgb[b * 3 + 2] = s2 + bg;
    }
}

extern "C" void kernel_launch(void* const* d_in, const int* in_sizes, int n_in,
                              void* d_out, int out_size, void* d_ws, size_t ws_size,
                              hipStream_t stream) {
    const float* rays_o   = (const float*)d_in[0];
    const float* rays_d   = (const float*)d_in[1];
    const float* grid     = (const float*)d_in[2];
    const float* codebook = (const float*)d_in[3];
    const float* W1       = (const float*)d_in[4];
    const float* b1       = (const float*)d_in[5];
    const float* W2       = (const float*)d_in[6];
    const float* b2       = (const float*)d_in[7];
    float* out = (float*)d_out;

    float* W1dT = (float*)d_ws;   // 128*16 f32 = 8 KB

    w1_prep_kernel<<<1, 128, 0, stream>>>(W1, W1dT);
    nerf_main_kernel<<<BATCH, NT, 0, stream>>>(
        rays_o, rays_d, grid, codebook, W1, b1, W2, b2, W1dT,
        out /* rgb: 1024*3 */, out + BATCH * 3 /* alpha: 1024*442 */);
}